// Round 14
// baseline (336.551 us; speedup 1.0000x reference)
//
#include <hip/hip_runtime.h>
#include <math.h>

#define NTOK 16384      // 4 * 4096 tokens
#define DIM 2048
#define NEXP 64
#define TOPK 8
#define BT 64           // tokens per tile (lane = token)
#define KC 64           // four numpy 16-blocks per stage
#define NCHUNK (DIM / KC)   // 32
#define PADK 68         // LDS row stride floats
#define EPW 4           // experts per wave
#define NTILE (NTOK / BT)   // 256 tiles

typedef float f2 __attribute__((ext_vector_type(2)));
typedef float f4 __attribute__((ext_vector_type(4)));

// VOP3P packed f32: two independent IEEE f32 ops per instr, component-wise
// bit-identical to the scalar sequence they replace.
__device__ __forceinline__ f2 pk_mul_sv(f2 bs, f2 av) {
    f2 d; asm("v_pk_mul_f32 %0, %1, %2" : "=v"(d) : "s"(bs), "v"(av)); return d;
}
__device__ __forceinline__ f2 pk_add(f2 a, f2 b) {
    f2 d; asm("v_pk_add_f32 %0, %1, %2" : "=v"(d) : "v"(a), "v"(b)); return d;
}

// ---------- fused kernel: GEMM -> logits; last half-block does softmax ----------
// grid 512 = 256 token-tiles x 2 expert-halves; 512 thr = 8 waves; 2 blocks/CU.
__global__ __launch_bounds__(512, 4) void moe_gemm_fused(
    const float* __restrict__ h, const float* __restrict__ W,
    float* __restrict__ out, float* __restrict__ wsum,
    int* __restrict__ flags, float* __restrict__ lgout)
{
#pragma clang fp contract(off)
    __shared__ float sA[2][BT * PADK];       // double-buffered h tile, 34.8 KB
    __shared__ float ls[8][NEXP + 2];        // softmax p rows (winner only)
    __shared__ int swin, sdone;

    const int tid  = threadIdx.x;            // 0..511
    const int lane = tid & 63;               // token within tile
    const int wv   = tid >> 6;               // 0..7
    const int tile = blockIdx.x >> 1;
    const int hf   = blockIdx.x & 1;         // expert half
    const long tok0 = (long)tile * BT;
    const float* hA = h + tok0 * DIM;

    const int e0 = __builtin_amdgcn_readfirstlane(hf * 32 + wv * EPW);
    const float* wb = W + (long)e0 * DIM;    // uniform -> s_load

    // staging map: 2 f4 per thread per stage (64 rows x 64 cols)
    const int rs0 = tid >> 4;                // 0..31
    const int cs0 = (tid & 15) * 4;          // 0..60

    // stage 0: load + write buf0; prefetch stage 1 into regs
    f4 ra = *(const f4*)(hA + (long)rs0 * DIM + cs0);
    f4 rb = *(const f4*)(hA + (long)(rs0 + 32) * DIM + cs0);
    *(f4*)&sA[0][rs0 * PADK + cs0]        = ra;
    *(f4*)&sA[0][(rs0 + 32) * PADK + cs0] = rb;
    ra = *(const f4*)(hA + (long)rs0 * DIM + KC + cs0);
    rb = *(const f4*)(hA + (long)(rs0 + 32) * DIM + KC + cs0);

    f2 a01[EPW], a23[EPW];
    #pragma unroll
    for (int j = 0; j < EPW; ++j) { a01[j] = (f2)(0.f); a23[j] = (f2)(0.f); }

    for (int kc = 0; kc < NCHUNK; ++kc) {
        __syncthreads();                     // one barrier per stage
        const int cur = kc & 1;

        if (kc + 1 < NCHUNK) {               // write next stage (regs -> LDS)
            *(f4*)&sA[cur ^ 1][rs0 * PADK + cs0]        = ra;
            *(f4*)&sA[cur ^ 1][(rs0 + 32) * PADK + cs0] = rb;
        }
        if (kc + 2 < NCHUNK) {               // prefetch stage kc+2 (vmcnt-counted)
            const long ko = (long)(kc + 2) * KC;
            ra = *(const f4*)(hA + (long)rs0 * DIM + ko + cs0);
            rb = *(const f4*)(hA + (long)(rs0 + 32) * DIM + ko + cs0);
        }

        // 4 numpy 16-blocks, strictly ascending k
        #pragma unroll
        for (int s = 0; s < 4; ++s) {
            const int kb = kc * KC + s * 16;

            // B: 4 experts x 16 floats, wave-uniform -> s_load (SGPRs)
            f4 B[EPW][4];
            #pragma unroll
            for (int j = 0; j < EPW; ++j)
                #pragma unroll
                for (int q = 0; q < 4; ++q)
                    B[j][q] = *(const f4*)(wb + (long)j * DIM + kb + 4 * q);

            // A: this lane's token (4 x ds_read_b128)
            f4 af[4];
            const float* ab = &sA[cur][lane * PADK + s * 16];
            #pragma unroll
            for (int v = 0; v < 4; ++v) af[v] = *(const f4*)(ab + 4 * v);

            f2 alo[4], ahi[4];               // .xy -> chains 0,1 ; .zw -> 2,3
            #pragma unroll
            for (int v = 0; v < 4; ++v) {
                alo[v] = __builtin_shufflevector(af[v], af[v], 0, 1);
                ahi[v] = __builtin_shufflevector(af[v], af[v], 2, 3);
            }

            #pragma unroll
            for (int j = 0; j < EPW; ++j) {
                f2 blo[4], bhi[4];           // uniform values (SGPR pairs)
                #pragma unroll
                for (int v = 0; v < 4; ++v) {
                    blo[v] = __builtin_shufflevector(B[j][v], B[j][v], 0, 1);
                    bhi[v] = __builtin_shufflevector(B[j][v], B[j][v], 2, 3);
                }
                f2 t;
                // chains 0,1: c = p0 + (p1 + (p2 + (p3 + c)))
                t = pk_add(pk_mul_sv(blo[3], alo[3]), a01[j]);
                t = pk_add(pk_mul_sv(blo[2], alo[2]), t);
                t = pk_add(pk_mul_sv(blo[1], alo[1]), t);
                a01[j] = pk_add(pk_mul_sv(blo[0], alo[0]), t);
                // chains 2,3
                t = pk_add(pk_mul_sv(bhi[3], ahi[3]), a23[j]);
                t = pk_add(pk_mul_sv(bhi[2], ahi[2]), t);
                t = pk_add(pk_mul_sv(bhi[1], ahi[1]), t);
                a23[j] = pk_add(pk_mul_sv(bhi[0], ahi[0]), t);
            }
        }
    }

    // horizontal combine: (c0+c2)+(c1+c3) -> global logits
    #pragma unroll
    for (int j = 0; j < EPW; ++j) {
        f2 s2 = pk_add(a01[j], a23[j]);      // (c0+c2, c1+c3)
        lgout[(tok0 + lane) * NEXP + e0 + j] = s2.x + s2.y;
    }

    // ---- elect last half-block of this tile (wait-free) ----
    __threadfence();                         // own logit stores -> device scope
    __syncthreads();                         // all threads fenced
    if (tid == 0) swin = atomicAdd(&flags[tile], 1);
    __syncthreads();
    if (swin != 1) return;                   // first arriver exits

    // ---- winner: softmax + top-8 + aux partials (verbatim verified code) ----
    float auxacc = 0.f;
    for (int tt = 0; tt < 8; ++tt) {
        const long gt = tok0 + wv * 8 + tt;
        // agent-scope load: bypass per-XCD L2 (other half may be on another XCD;
        // L2 may also hold stale clean lines from the previous graph replay)
        const float s = __hip_atomic_load(&lgout[gt * NEXP + lane],
                                          __ATOMIC_RELAXED, __HIP_MEMORY_SCOPE_AGENT);

        float m = s;                          // max: exact, order-independent
        #pragma unroll
        for (int off = 32; off >= 1; off >>= 1)
            m = fmaxf(m, __shfl_xor(m, off));

        const float p = expf(s - m);
        ls[wv][lane] = p;                     // own wave's row only
        __asm__ volatile("" ::: "memory");    // compiler barrier; DS in-order per wave

        // np.sum pairwise, n=64: 8 stride-8 serial chains + fixed combine
        float r0s = ls[wv][0], r1s = ls[wv][1], r2s = ls[wv][2], r3s = ls[wv][3];
        float r4s = ls[wv][4], r5s = ls[wv][5], r6s = ls[wv][6], r7s = ls[wv][7];
        #pragma unroll
        for (int i = 1; i < 8; ++i) {
            r0s += ls[wv][8 * i + 0]; r1s += ls[wv][8 * i + 1];
            r2s += ls[wv][8 * i + 2]; r3s += ls[wv][8 * i + 3];
            r4s += ls[wv][8 * i + 4]; r5s += ls[wv][8 * i + 5];
            r6s += ls[wv][8 * i + 6]; r7s += ls[wv][8 * i + 7];
        }
        const float S = ((r0s + r1s) + (r2s + r3s)) + ((r4s + r5s) + (r6s + r7s));

        const float score = p / S;            // IEEE f32 divide, matches np
        auxacc += score;

        // stable top-8: max with lowest-index tie-break (stable argsort)
        float cv = score;
        float myv = 0.f;
        int   myi = 0;
        #pragma unroll
        for (int i = 0; i < TOPK; ++i) {
            float v = cv;
            int idx = lane;
            #pragma unroll
            for (int off = 32; off >= 1; off >>= 1) {
                float v2 = __shfl_xor(v, off);
                int   i2 = __shfl_xor(idx, off);
                if (v2 > v || (v2 == v && i2 < idx)) { v = v2; idx = i2; }
            }
            if (lane == i)   { myv = v; myi = idx; }
            if (lane == idx) cv = -1.f;       // scores >= 0
        }

        // weight denom: np.sum n=8 -> serial ascending
        float S8 = 0.f;
        #pragma unroll
        for (int r = 0; r < TOPK; ++r) S8 += __shfl(myv, r);

        if (lane < TOPK) {
            const long o = gt * TOPK + lane;
            out[o]                     = (float)myi;   // expert_ids
            out[(long)NTOK * TOPK + o] = myv / S8;     // expert_weight
        }
    }
    atomicAdd(&wsum[(tile >> 6) * NEXP + lane], auxacc);

    // ---- elect last tile overall; it computes the final aux loss ----
    __threadfence();
    __syncthreads();
    if (tid == 0) sdone = atomicAdd(&flags[NTILE], 1);
    __syncthreads();
    if (sdone == NTILE - 1 && tid < 64) {
        float a = 0.f;
        #pragma unroll
        for (int b = 0; b < 4; ++b) {
            // atomic read-at-coherent-point (value unchanged: +0.0f)
            const float v = atomicAdd(&wsum[b * NEXP + tid], 0.f) * (1.0f / 4096.0f);
            a = fmaf(v, v, a);
        }
        #pragma unroll
        for (int off = 32; off >= 1; off >>= 1)
            a += __shfl_xor(a, off);
        if (tid == 0)
            out[2L * NTOK * TOPK] = a * 0.25f * (float)NEXP * 0.01f;
    }
}

// ---------- fallback monolith (verified R10 kernel, used if ws too small) ----------
__global__ __launch_bounds__(1024, 1) void moe_gate_np(
    const float* __restrict__ h, const float* __restrict__ W,
    float* __restrict__ out, float* __restrict__ wsum)
{
#pragma clang fp contract(off)
    __shared__ float sA[BT * PADK];
    __shared__ float lg[BT][NEXP + 2];

    const int tid  = threadIdx.x;
    const int lane = tid & 63;
    const int wv   = tid >> 6;
    const int blk  = blockIdx.x;
    const long tok0 = (long)blk * BT;
    const float* hA = h + tok0 * DIM;

    const int e0 = __builtin_amdgcn_readfirstlane(wv) * EPW;
    const float* wb = W + (long)e0 * DIM;

    const int rs = tid >> 4;
    const int cs = (tid & 15) * 4;
    f4 pa = *(const f4*)(hA + (long)rs * DIM + cs);

    f2 a01[EPW], a23[EPW];
    #pragma unroll
    for (int j = 0; j < EPW; ++j) { a01[j] = (f2)(0.f); a23[j] = (f2)(0.f); }

    for (int kc = 0; kc < NCHUNK; ++kc) {
        __syncthreads();
        *(f4*)&sA[rs * PADK + cs] = pa;
        __syncthreads();
        if (kc + 1 < NCHUNK)
            pa = *(const f4*)(hA + (long)rs * DIM + (long)(kc + 1) * KC + cs);

        #pragma unroll
        for (int s = 0; s < 4; ++s) {
            const int kb = kc * KC + s * 16;
            f4 B[EPW][4];
            #pragma unroll
            for (int j = 0; j < EPW; ++j)
                #pragma unroll
                for (int q = 0; q < 4; ++q)
                    B[j][q] = *(const f4*)(wb + (long)j * DIM + kb + 4 * q);
            f4 af[4];
            const float* ab = &sA[lane * PADK + s * 16];
            #pragma unroll
            for (int v = 0; v < 4; ++v) af[v] = *(const f4*)(ab + 4 * v);
            f2 alo[4], ahi[4];
            #pragma unroll
            for (int v = 0; v < 4; ++v) {
                alo[v] = __builtin_shufflevector(af[v], af[v], 0, 1);
                ahi[v] = __builtin_shufflevector(af[v], af[v], 2, 3);
            }
            #pragma unroll
            for (int j = 0; j < EPW; ++j) {
                f2 blo[4], bhi[4];
                #pragma unroll
                for (int v = 0; v < 4; ++v) {
                    blo[v] = __builtin_shufflevector(B[j][v], B[j][v], 0, 1);
                    bhi[v] = __builtin_shufflevector(B[j][v], B[j][v], 2, 3);
                }
                f2 t;
                t = pk_add(pk_mul_sv(blo[3], alo[3]), a01[j]);
                t = pk_add(pk_mul_sv(blo[2], alo[2]), t);
                t = pk_add(pk_mul_sv(blo[1], alo[1]), t);
                a01[j] = pk_add(pk_mul_sv(blo[0], alo[0]), t);
                t = pk_add(pk_mul_sv(bhi[3], ahi[3]), a23[j]);
                t = pk_add(pk_mul_sv(bhi[2], ahi[2]), t);
                t = pk_add(pk_mul_sv(bhi[1], ahi[1]), t);
                a23[j] = pk_add(pk_mul_sv(bhi[0], ahi[0]), t);
            }
        }
    }

    #pragma unroll
    for (int j = 0; j < EPW; ++j) {
        f2 s2 = pk_add(a01[j], a23[j]);
        lg[lane][e0 + j] = s2.x + s2.y;
    }
    __syncthreads();

    float auxacc = 0.f;
    for (int tt = 0; tt < 4; ++tt) {
        const int t = wv * 4 + tt;
        const float s = lg[t][lane];
        float m = s;
        #pragma unroll
        for (int off = 32; off >= 1; off >>= 1)
            m = fmaxf(m, __shfl_xor(m, off));
        const float p = expf(s - m);
        lg[t][lane] = p;
        __asm__ volatile("" ::: "memory");
        float r0s = lg[t][0], r1s = lg[t][1], r2s = lg[t][2], r3s = lg[t][3];
        float r4s = lg[t][4], r5s = lg[t][5], r6s = lg[t][6], r7s = lg[t][7];
        #pragma unroll
        for (int i = 1; i < 8; ++i) {
            r0s += lg[t][8 * i + 0]; r1s += lg[t][8 * i + 1];
            r2s += lg[t][8 * i + 2]; r3s += lg[t][8 * i + 3];
            r4s += lg[t][8 * i + 4]; r5s += lg[t][8 * i + 5];
            r6s += lg[t][8 * i + 6]; r7s += lg[t][8 * i + 7];
        }
        const float S = ((r0s + r1s) + (r2s + r3s)) + ((r4s + r5s) + (r6s + r7s));
        const float score = p / S;
        auxacc += score;
        float cv = score;
        float myv = 0.f;
        int   myi = 0;
        #pragma unroll
        for (int i = 0; i < TOPK; ++i) {
            float v = cv;
            int idx = lane;
            #pragma unroll
            for (int off = 32; off >= 1; off >>= 1) {
                float v2 = __shfl_xor(v, off);
                int   i2 = __shfl_xor(idx, off);
                if (v2 > v || (v2 == v && i2 < idx)) { v = v2; idx = i2; }
            }
            if (lane == i)   { myv = v; myi = idx; }
            if (lane == idx) cv = -1.f;
        }
        float S8 = 0.f;
        #pragma unroll
        for (int r = 0; r < TOPK; ++r) S8 += __shfl(myv, r);
        if (lane < TOPK) {
            const long o = (tok0 + t) * TOPK + lane;
            out[o]                     = (float)myi;
            out[(long)NTOK * TOPK + o] = myv / S8;
        }
    }
    atomicAdd(&wsum[(blk >> 6) * NEXP + lane], auxacc);
}

__global__ void aux_finish(const float* __restrict__ wsum, float* __restrict__ out)
{
    const int lane = threadIdx.x;            // 64 threads
    float a = 0.f;
    #pragma unroll
    for (int b = 0; b < 4; ++b) {
        const float v = wsum[b * NEXP + lane] * (1.0f / 4096.0f);
        a = fmaf(v, v, a);
    }
    #pragma unroll
    for (int off = 32; off >= 1; off >>= 1)
        a += __shfl_xor(a, off);
    if (lane == 0)
        out[2L * NTOK * TOPK] = a * 0.25f * (float)NEXP * 0.01f;
}

extern "C" void kernel_launch(void* const* d_in, const int* in_sizes, int n_in,
                              void* d_out, int out_size, void* d_ws, size_t ws_size,
                              hipStream_t stream) {
    const float* h = (const float*)d_in[0];
    const float* W = (const float*)d_in[1];
    float* out  = (float*)d_out;
    float* wsum = (float*)d_ws;              // 256 f32 @ offset 0
    int*   flags = (int*)((char*)d_ws + 4096);   // 256 tile flags + done counter
    float* lgout = (float*)((char*)d_ws + 8192); // 4 MB logits

    const size_t need = 8192 + (size_t)NTOK * NEXP * sizeof(float);

    hipMemsetAsync(d_ws, 0, 8192, stream);   // wsum + flags + done
    if (ws_size >= need) {
        moe_gemm_fused<<<NTILE * 2, 512, 0, stream>>>(h, W, out, wsum, flags, lgout);
    } else {
        moe_gate_np<<<NTOK / BT, 1024, 0, stream>>>(h, W, out, wsum);
        aux_finish<<<1, 64, 0, stream>>>(wsum, out);
    }
}

// Round 15
// 205.438 us; speedup vs baseline: 1.6382x; 1.6382x over previous
//
#include <hip/hip_runtime.h>
#include <math.h>

#define NTOK 16384      // 4 * 4096 tokens
#define DIM 2048
#define NEXP 64
#define TOPK 8
#define TT 128          // tokens per tile (2 per lane: lane, lane+64)
#define KC 32           // two numpy 16-blocks per stage
#define NCHUNK (DIM / KC)   // 64
#define PADK 36         // LDS row stride floats (9-granule odd stride)
#define EPW 4           // experts per wave
#define NTILE (NTOK / TT)   // 128 tiles

typedef float f2 __attribute__((ext_vector_type(2)));
typedef float f4 __attribute__((ext_vector_type(4)));

// VOP3P packed f32: two independent IEEE f32 ops per instr, component-wise
// bit-identical to the scalar sequence they replace.
__device__ __forceinline__ f2 pk_mul_sv(f2 bs, f2 av) {
    f2 d; asm("v_pk_mul_f32 %0, %1, %2" : "=v"(d) : "s"(bs), "v"(av)); return d;
}
__device__ __forceinline__ f2 pk_add(f2 a, f2 b) {
    f2 d; asm("v_pk_add_f32 %0, %1, %2" : "=v"(d) : "v"(a), "v"(b)); return d;
}

// ---------- kernel 1: GEMM -> global logits ----------
// grid 512 = 128 token-tiles x 4 expert-quarters; 256 thr = 4 waves; 2 blocks/CU.
// Each wave: 128 tokens (2/lane) x 4 experts -> 256cy MAC per SMEM exposure.
__global__ __launch_bounds__(256, 2) void moe_gemm(
    const float* __restrict__ h, const float* __restrict__ W,
    float* __restrict__ lgout)
{
#pragma clang fp contract(off)
    __shared__ float sA[2][TT * PADK];       // double-buffered h tile, 36.9 KB

    const int tid  = threadIdx.x;            // 0..255
    const int lane = tid & 63;
    const int wv   = tid >> 6;               // 0..3
    const int tile = blockIdx.x >> 2;
    const int qt   = blockIdx.x & 3;         // expert quarter
    const long tok0 = (long)tile * TT;
    const float* hA = h + tok0 * DIM;

    const int e0 = __builtin_amdgcn_readfirstlane(qt * 16 + wv * EPW);
    const float* wb = W + (long)e0 * DIM;    // uniform -> s_load

    // staging map: 4 f4 per thread per stage (128 rows x 32 cols)
    // idx = tid + 256q: row = idx>>3, col = (idx&7)*4
    f4 pa[4];
    #pragma unroll
    for (int q = 0; q < 4; ++q) {
        const int idx = tid + 256 * q;
        pa[q] = *(const f4*)(hA + (long)(idx >> 3) * DIM + (idx & 7) * 4);
    }
    #pragma unroll
    for (int q = 0; q < 4; ++q) {
        const int idx = tid + 256 * q;
        *(f4*)&sA[0][(idx >> 3) * PADK + (idx & 7) * 4] = pa[q];
    }
    #pragma unroll
    for (int q = 0; q < 4; ++q) {            // prefetch stage 1
        const int idx = tid + 256 * q;
        pa[q] = *(const f4*)(hA + (long)(idx >> 3) * DIM + KC + (idx & 7) * 4);
    }

    // accumulators: 2 tokens x 4 experts x chain pairs (c0,c1)/(c2,c3)
    f2 a01[2][EPW], a23[2][EPW];
    #pragma unroll
    for (int t = 0; t < 2; ++t)
        #pragma unroll
        for (int j = 0; j < EPW; ++j) { a01[t][j] = (f2)(0.f); a23[t][j] = (f2)(0.f); }

    for (int kc = 0; kc < NCHUNK; ++kc) {
        __syncthreads();                     // one barrier per stage
        const int cur = kc & 1;

        if (kc + 1 < NCHUNK) {               // write next stage (regs -> LDS)
            #pragma unroll
            for (int q = 0; q < 4; ++q) {
                const int idx = tid + 256 * q;
                *(f4*)&sA[cur ^ 1][(idx >> 3) * PADK + (idx & 7) * 4] = pa[q];
            }
        }
        if (kc + 2 < NCHUNK) {               // prefetch stage kc+2 (vmcnt-counted)
            const long ko = (long)(kc + 2) * KC;
            #pragma unroll
            for (int q = 0; q < 4; ++q) {
                const int idx = tid + 256 * q;
                pa[q] = *(const f4*)(hA + (long)(idx >> 3) * DIM + ko + (idx & 7) * 4);
            }
        }

        // 2 numpy 16-blocks per stage, strictly ascending k
        #pragma unroll
        for (int s = 0; s < 2; ++s) {
            const int kb = kc * KC + s * 16;

            // B: 4 experts x 16 floats, wave-uniform -> s_load (64 SGPR)
            f4 B[EPW][4];
            #pragma unroll
            for (int j = 0; j < EPW; ++j)
                #pragma unroll
                for (int q = 0; q < 4; ++q)
                    B[j][q] = *(const f4*)(wb + (long)j * DIM + kb + 4 * q);

            // A: this lane's 2 tokens (8 x ds_read_b128)
            f4 af[2][4];
            #pragma unroll
            for (int t = 0; t < 2; ++t) {
                const float* ab = &sA[cur][(lane + 64 * t) * PADK + s * 16];
                #pragma unroll
                for (int v = 0; v < 4; ++v) af[t][v] = *(const f4*)(ab + 4 * v);
            }

            #pragma unroll
            for (int t = 0; t < 2; ++t) {
                f2 alo[4], ahi[4];           // .xy -> chains 0,1 ; .zw -> 2,3
                #pragma unroll
                for (int v = 0; v < 4; ++v) {
                    alo[v] = __builtin_shufflevector(af[t][v], af[t][v], 0, 1);
                    ahi[v] = __builtin_shufflevector(af[t][v], af[t][v], 2, 3);
                }
                #pragma unroll
                for (int j = 0; j < EPW; ++j) {
                    f2 blo[4], bhi[4];       // uniform values (SGPR pairs)
                    #pragma unroll
                    for (int v = 0; v < 4; ++v) {
                        blo[v] = __builtin_shufflevector(B[j][v], B[j][v], 0, 1);
                        bhi[v] = __builtin_shufflevector(B[j][v], B[j][v], 2, 3);
                    }
                    f2 x;
                    // chains 0,1: c = p0 + (p1 + (p2 + (p3 + c)))
                    x = pk_add(pk_mul_sv(blo[3], alo[3]), a01[t][j]);
                    x = pk_add(pk_mul_sv(blo[2], alo[2]), x);
                    x = pk_add(pk_mul_sv(blo[1], alo[1]), x);
                    a01[t][j] = pk_add(pk_mul_sv(blo[0], alo[0]), x);
                    // chains 2,3
                    x = pk_add(pk_mul_sv(bhi[3], ahi[3]), a23[t][j]);
                    x = pk_add(pk_mul_sv(bhi[2], ahi[2]), x);
                    x = pk_add(pk_mul_sv(bhi[1], ahi[1]), x);
                    a23[t][j] = pk_add(pk_mul_sv(bhi[0], ahi[0]), x);
                }
            }
        }
    }

    // horizontal combine: (c0+c2)+(c1+c3) -> global logits (one f4 per token)
    #pragma unroll
    for (int t = 0; t < 2; ++t) {
        f4 o4;
        #pragma unroll
        for (int j = 0; j < EPW; ++j) {
            f2 s2 = pk_add(a01[t][j], a23[t][j]);   // (c0+c2, c1+c3)
            o4[j] = s2.x + s2.y;
        }
        *(f4*)&lgout[(tok0 + lane + 64 * t) * NEXP + e0] = o4;
    }
}

// ---------- kernel 2: softmax + top-8 + aux partials (verbatim verified) ----------
__global__ __launch_bounds__(512) void softmax_topk(
    const float* __restrict__ lgout, float* __restrict__ out,
    float* __restrict__ wsum)
{
    __shared__ float ls[8][NEXP + 2];
    const int tid  = threadIdx.x;
    const int lane = tid & 63;               // lane = expert
    const int wv8  = tid >> 6;               // 0..7
    const int blk  = blockIdx.x;
    const long tok0 = (long)blk * 64;
    float auxacc = 0.f;

    for (int tt = 0; tt < 8; ++tt) {
        const long gt = tok0 + wv8 * 8 + tt;
        const float s = lgout[gt * NEXP + lane];

        float m = s;                          // max: exact, order-independent
        #pragma unroll
        for (int off = 32; off >= 1; off >>= 1)
            m = fmaxf(m, __shfl_xor(m, off));

        const float p = expf(s - m);
        ls[wv8][lane] = p;                    // own wave's row only
        __asm__ volatile("" ::: "memory");    // compiler barrier; DS in-order per wave

        // np.sum pairwise, n=64: 8 stride-8 serial chains + fixed combine
        float r0s = ls[wv8][0], r1s = ls[wv8][1], r2s = ls[wv8][2], r3s = ls[wv8][3];
        float r4s = ls[wv8][4], r5s = ls[wv8][5], r6s = ls[wv8][6], r7s = ls[wv8][7];
        #pragma unroll
        for (int i = 1; i < 8; ++i) {
            r0s += ls[wv8][8 * i + 0]; r1s += ls[wv8][8 * i + 1];
            r2s += ls[wv8][8 * i + 2]; r3s += ls[wv8][8 * i + 3];
            r4s += ls[wv8][8 * i + 4]; r5s += ls[wv8][8 * i + 5];
            r6s += ls[wv8][8 * i + 6]; r7s += ls[wv8][8 * i + 7];
        }
        const float S = ((r0s + r1s) + (r2s + r3s)) + ((r4s + r5s) + (r6s + r7s));

        const float score = p / S;            // IEEE f32 divide, matches np
        auxacc += score;

        // stable top-8: max with lowest-index tie-break (stable argsort)
        float cv = score;
        float myv = 0.f;
        int   myi = 0;
        #pragma unroll
        for (int i = 0; i < TOPK; ++i) {
            float v = cv;
            int idx = lane;
            #pragma unroll
            for (int off = 32; off >= 1; off >>= 1) {
                float v2 = __shfl_xor(v, off);
                int   i2 = __shfl_xor(idx, off);
                if (v2 > v || (v2 == v && i2 < idx)) { v = v2; idx = i2; }
            }
            if (lane == i)   { myv = v; myi = idx; }
            if (lane == idx) cv = -1.f;       // scores >= 0
        }

        // weight denom: np.sum n=8 -> serial ascending
        float S8 = 0.f;
        #pragma unroll
        for (int r = 0; r < TOPK; ++r) S8 += __shfl(myv, r);

        if (lane < TOPK) {
            const long o = gt * TOPK + lane;
            out[o]                     = (float)myi;   // expert_ids
            out[(long)NTOK * TOPK + o] = myv / S8;     // expert_weight
        }
    }

    atomicAdd(&wsum[(blk >> 6) * NEXP + lane], auxacc);
}

__global__ void aux_finish(const float* __restrict__ wsum, float* __restrict__ out)
{
    const int lane = threadIdx.x;            // 64 threads
    float a = 0.f;
    #pragma unroll
    for (int b = 0; b < 4; ++b) {
        const float v = wsum[b * NEXP + lane] * (1.0f / 4096.0f);
        a = fmaf(v, v, a);
    }
    #pragma unroll
    for (int off = 32; off >= 1; off >>= 1)
        a += __shfl_xor(a, off);
    if (lane == 0)
        out[2L * NTOK * TOPK] = a * 0.25f * (float)NEXP * 0.01f;
}

// ---------- fallback monolith (verified R10 kernel, used if ws too small) ----------
#define BT 64
#define KCM 64
#define PADKM 68
__global__ __launch_bounds__(1024, 1) void moe_gate_np(
    const float* __restrict__ h, const float* __restrict__ W,
    float* __restrict__ out, float* __restrict__ wsum)
{
#pragma clang fp contract(off)
    __shared__ float sA[BT * PADKM];
    __shared__ float lg[BT][NEXP + 2];

    const int tid  = threadIdx.x;
    const int lane = tid & 63;
    const int wv   = tid >> 6;
    const int blk  = blockIdx.x;
    const long tok0 = (long)blk * BT;
    const float* hA = h + tok0 * DIM;

    const int e0 = __builtin_amdgcn_readfirstlane(wv) * EPW;
    const float* wb = W + (long)e0 * DIM;

    const int rs = tid >> 4;
    const int cs = (tid & 15) * 4;
    f4 pa = *(const f4*)(hA + (long)rs * DIM + cs);

    f2 a01[EPW], a23[EPW];
    #pragma unroll
    for (int j = 0; j < EPW; ++j) { a01[j] = (f2)(0.f); a23[j] = (f2)(0.f); }

    for (int kc = 0; kc < DIM / KCM; ++kc) {
        __syncthreads();
        *(f4*)&sA[rs * PADKM + cs] = pa;
        __syncthreads();
        if (kc + 1 < DIM / KCM)
            pa = *(const f4*)(hA + (long)rs * DIM + (long)(kc + 1) * KCM + cs);

        #pragma unroll
        for (int s = 0; s < 4; ++s) {
            const int kb = kc * KCM + s * 16;
            f4 B[EPW][4];
            #pragma unroll
            for (int j = 0; j < EPW; ++j)
                #pragma unroll
                for (int q = 0; q < 4; ++q)
                    B[j][q] = *(const f4*)(wb + (long)j * DIM + kb + 4 * q);
            f4 af[4];
            const float* ab = &sA[lane * PADKM + s * 16];
            #pragma unroll
            for (int v = 0; v < 4; ++v) af[v] = *(const f4*)(ab + 4 * v);
            f2 alo[4], ahi[4];
            #pragma unroll
            for (int v = 0; v < 4; ++v) {
                alo[v] = __builtin_shufflevector(af[v], af[v], 0, 1);
                ahi[v] = __builtin_shufflevector(af[v], af[v], 2, 3);
            }
            #pragma unroll
            for (int j = 0; j < EPW; ++j) {
                f2 blo[4], bhi[4];
                #pragma unroll
                for (int v = 0; v < 4; ++v) {
                    blo[v] = __builtin_shufflevector(B[j][v], B[j][v], 0, 1);
                    bhi[v] = __builtin_shufflevector(B[j][v], B[j][v], 2, 3);
                }
                f2 x;
                x = pk_add(pk_mul_sv(blo[3], alo[3]), a01[j]);
                x = pk_add(pk_mul_sv(blo[2], alo[2]), x);
                x = pk_add(pk_mul_sv(blo[1], alo[1]), x);
                a01[j] = pk_add(pk_mul_sv(blo[0], alo[0]), x);
                x = pk_add(pk_mul_sv(bhi[3], ahi[3]), a23[j]);
                x = pk_add(pk_mul_sv(bhi[2], ahi[2]), x);
                x = pk_add(pk_mul_sv(bhi[1], ahi[1]), x);
                a23[j] = pk_add(pk_mul_sv(bhi[0], ahi[0]), x);
            }
        }
    }

    #pragma unroll
    for (int j = 0; j < EPW; ++j) {
        f2 s2 = pk_add(a01[j], a23[j]);
        lg[lane][e0 + j] = s2.x + s2.y;
    }
    __syncthreads();

    float auxacc = 0.f;
    for (int tt = 0; tt < 4; ++tt) {
        const int t = wv * 4 + tt;
        const float s = lg[t][lane];
        float m = s;
        #pragma unroll
        for (int off = 32; off >= 1; off >>= 1)
            m = fmaxf(m, __shfl_xor(m, off));
        const float p = expf(s - m);
        lg[t][lane] = p;
        __asm__ volatile("" ::: "memory");
        float r0s = lg[t][0], r1s = lg[t][1], r2s = lg[t][2], r3s = lg[t][3];
        float r4s = lg[t][4], r5s = lg[t][5], r6s = lg[t][6], r7s = lg[t][7];
        #pragma unroll
        for (int i = 1; i < 8; ++i) {
            r0s += lg[t][8 * i + 0]; r1s += lg[t][8 * i + 1];
            r2s += lg[t][8 * i + 2]; r3s += lg[t][8 * i + 3];
            r4s += lg[t][8 * i + 4]; r5s += lg[t][8 * i + 5];
            r6s += lg[t][8 * i + 6]; r7s += lg[t][8 * i + 7];
        }
        const float S = ((r0s + r1s) + (r2s + r3s)) + ((r4s + r5s) + (r6s + r7s));
        const float score = p / S;
        auxacc += score;
        float cv = score;
        float myv = 0.f;
        int   myi = 0;
        #pragma unroll
        for (int i = 0; i < TOPK; ++i) {
            float v = cv;
            int idx = lane;
            #pragma unroll
            for (int off = 32; off >= 1; off >>= 1) {
                float v2 = __shfl_xor(v, off);
                int   i2 = __shfl_xor(idx, off);
                if (v2 > v || (v2 == v && i2 < idx)) { v = v2; idx = i2; }
            }
            if (lane == i)   { myv = v; myi = idx; }
            if (lane == idx) cv = -1.f;
        }
        float S8 = 0.f;
        #pragma unroll
        for (int r = 0; r < TOPK; ++r) S8 += __shfl(myv, r);
        if (lane < TOPK) {
            const long o = (tok0 + t) * TOPK + lane;
            out[o]                     = (float)myi;
            out[(long)NTOK * TOPK + o] = myv / S8;
        }
    }
    atomicAdd(&wsum[(blk >> 6) * NEXP + lane], auxacc);
}

extern "C" void kernel_launch(void* const* d_in, const int* in_sizes, int n_in,
                              void* d_out, int out_size, void* d_ws, size_t ws_size,
                              hipStream_t stream) {
    const float* h = (const float*)d_in[0];
    const float* W = (const float*)d_in[1];
    float* out  = (float*)d_out;
    float* wsum = (float*)d_ws;              // 256 f32 @ offset 0

    const size_t need = 4096 + (size_t)NTOK * NEXP * sizeof(float);

    hipMemsetAsync(d_ws, 0, 1024, stream);
    if (ws_size >= need) {
        float* lgout = (float*)((char*)d_ws + 4096);   // 4 MB logits
        moe_gemm<<<NTILE * 4, 256, 0, stream>>>(h, W, lgout);
        softmax_topk<<<NTOK / 64, 512, 0, stream>>>(lgout, out, wsum);
    } else {
        moe_gate_np<<<NTOK / BT, 1024, 0, stream>>>(h, W, out, wsum);
    }
    aux_finish<<<1, 64, 0, stream>>>(wsum, out);
}

// Round 16
// 193.562 us; speedup vs baseline: 1.7387x; 1.0614x over previous
//
#include <hip/hip_runtime.h>
#include <math.h>

#define NTOK 16384      // 4 * 4096 tokens
#define DIM 2048
#define NEXP 64
#define TOPK 8
#define BT 64           // tokens per tile (lane = token)
#define KC 64           // four numpy 16-blocks per stage
#define NCHUNK (DIM / KC)   // 32
#define PADK 68         // LDS row stride floats
#define EPW 4           // experts per wave
#define NTILE (NTOK / BT)   // 256 tiles

typedef float f2 __attribute__((ext_vector_type(2)));
typedef float f4 __attribute__((ext_vector_type(4)));

// VOP3P packed f32: two independent IEEE f32 ops per instr, component-wise
// bit-identical to the scalar sequence they replace.
__device__ __forceinline__ f2 pk_mul_sv(f2 bs, f2 av) {
    f2 d; asm("v_pk_mul_f32 %0, %1, %2" : "=v"(d) : "s"(bs), "v"(av)); return d;
}
__device__ __forceinline__ f2 pk_add(f2 a, f2 b) {
    f2 d; asm("v_pk_add_f32 %0, %1, %2" : "=v"(d) : "v"(a), "v"(b)); return d;
}

// ---------- kernel 1: GEMM -> global logits ----------
// grid 1024 = 256 token-tiles x 4 expert-quarters; 256 thr = 4 waves; 4 blocks/CU.
// Small blocks decorrelate barriers: 4 independent groups per CU hide each
// other's SMEM-latency exposures (lgkmcnt(0) is all-or-nothing for s_load).
__global__ __launch_bounds__(256, 4) void moe_gemm(
    const float* __restrict__ h, const float* __restrict__ W,
    float* __restrict__ lgout)
{
#pragma clang fp contract(off)
    __shared__ float sA[2][BT * PADK];       // double-buffered h tile, 34.8 KB

    const int tid  = threadIdx.x;            // 0..255
    const int lane = tid & 63;               // token within tile
    const int wv   = tid >> 6;               // 0..3
    const int tile = blockIdx.x >> 2;
    const int qt   = blockIdx.x & 3;         // expert quarter
    const long tok0 = (long)tile * BT;
    const float* hA = h + tok0 * DIM;

    const int e0 = __builtin_amdgcn_readfirstlane(qt * 16 + wv * EPW);
    const float* wb = W + (long)e0 * DIM;    // uniform -> s_load

    // staging map: 4 f4 per thread per stage (64 rows x 64 cols)
    // idx = tid + 256q: row = idx>>4, col = (idx&15)*4
    f4 pa[4];
    #pragma unroll
    for (int q = 0; q < 4; ++q) {
        const int idx = tid + 256 * q;
        pa[q] = *(const f4*)(hA + (long)(idx >> 4) * DIM + (idx & 15) * 4);
    }
    #pragma unroll
    for (int q = 0; q < 4; ++q) {
        const int idx = tid + 256 * q;
        *(f4*)&sA[0][(idx >> 4) * PADK + (idx & 15) * 4] = pa[q];
    }
    #pragma unroll
    for (int q = 0; q < 4; ++q) {            // prefetch stage 1
        const int idx = tid + 256 * q;
        pa[q] = *(const f4*)(hA + (long)(idx >> 4) * DIM + KC + (idx & 15) * 4);
    }

    f2 a01[EPW], a23[EPW];
    #pragma unroll
    for (int j = 0; j < EPW; ++j) { a01[j] = (f2)(0.f); a23[j] = (f2)(0.f); }

    for (int kc = 0; kc < NCHUNK; ++kc) {
        __syncthreads();                     // one barrier per stage
        const int cur = kc & 1;

        if (kc + 1 < NCHUNK) {               // write next stage (regs -> LDS)
            #pragma unroll
            for (int q = 0; q < 4; ++q) {
                const int idx = tid + 256 * q;
                *(f4*)&sA[cur ^ 1][(idx >> 4) * PADK + (idx & 15) * 4] = pa[q];
            }
        }
        if (kc + 2 < NCHUNK) {               // prefetch stage kc+2 (vmcnt-counted)
            const long ko = (long)(kc + 2) * KC;
            #pragma unroll
            for (int q = 0; q < 4; ++q) {
                const int idx = tid + 256 * q;
                pa[q] = *(const f4*)(hA + (long)(idx >> 4) * DIM + ko + (idx & 15) * 4);
            }
        }

        // 4 numpy 16-blocks, strictly ascending k
        #pragma unroll
        for (int s = 0; s < 4; ++s) {
            const int kb = kc * KC + s * 16;

            // B: 4 experts x 16 floats, wave-uniform -> s_load (64 SGPR)
            f4 B[EPW][4];
            #pragma unroll
            for (int j = 0; j < EPW; ++j)
                #pragma unroll
                for (int q = 0; q < 4; ++q)
                    B[j][q] = *(const f4*)(wb + (long)j * DIM + kb + 4 * q);

            // A: this lane's token (4 x ds_read_b128)
            f4 af[4];
            const float* ab = &sA[cur][lane * PADK + s * 16];
            #pragma unroll
            for (int v = 0; v < 4; ++v) af[v] = *(const f4*)(ab + 4 * v);

            f2 alo[4], ahi[4];               // .xy -> chains 0,1 ; .zw -> 2,3
            #pragma unroll
            for (int v = 0; v < 4; ++v) {
                alo[v] = __builtin_shufflevector(af[v], af[v], 0, 1);
                ahi[v] = __builtin_shufflevector(af[v], af[v], 2, 3);
            }

            #pragma unroll
            for (int j = 0; j < EPW; ++j) {
                f2 blo[4], bhi[4];           // uniform values (SGPR pairs)
                #pragma unroll
                for (int v = 0; v < 4; ++v) {
                    blo[v] = __builtin_shufflevector(B[j][v], B[j][v], 0, 1);
                    bhi[v] = __builtin_shufflevector(B[j][v], B[j][v], 2, 3);
                }
                f2 x;
                // chains 0,1: c = p0 + (p1 + (p2 + (p3 + c)))
                x = pk_add(pk_mul_sv(blo[3], alo[3]), a01[j]);
                x = pk_add(pk_mul_sv(blo[2], alo[2]), x);
                x = pk_add(pk_mul_sv(blo[1], alo[1]), x);
                a01[j] = pk_add(pk_mul_sv(blo[0], alo[0]), x);
                // chains 2,3
                x = pk_add(pk_mul_sv(bhi[3], ahi[3]), a23[j]);
                x = pk_add(pk_mul_sv(bhi[2], ahi[2]), x);
                x = pk_add(pk_mul_sv(bhi[1], ahi[1]), x);
                a23[j] = pk_add(pk_mul_sv(bhi[0], ahi[0]), x);
            }
        }
    }

    // horizontal combine: (c0+c2)+(c1+c3) -> global logits (one f4 per token)
    f4 o4;
    #pragma unroll
    for (int j = 0; j < EPW; ++j) {
        f2 s2 = pk_add(a01[j], a23[j]);      // (c0+c2, c1+c3)
        o4[j] = s2.x + s2.y;
    }
    *(f4*)&lgout[(tok0 + lane) * NEXP + e0] = o4;
}

// ---------- kernel 2: softmax + top-8 + aux (fused; verbatim verified math) ----------
__global__ __launch_bounds__(512) void softmax_topk_aux(
    const float* __restrict__ lgout, float* __restrict__ out,
    float* __restrict__ wsum, int* __restrict__ done)
{
    __shared__ float ls[8][NEXP + 2];
    __shared__ int sdone;
    const int tid  = threadIdx.x;
    const int lane = tid & 63;               // lane = expert
    const int wv8  = tid >> 6;               // 0..7
    const int blk  = blockIdx.x;
    const long tok0 = (long)blk * 64;
    float auxacc = 0.f;

    for (int tt = 0; tt < 8; ++tt) {
        const long gt = tok0 + wv8 * 8 + tt;
        const float s = lgout[gt * NEXP + lane];

        float m = s;                          // max: exact, order-independent
        #pragma unroll
        for (int off = 32; off >= 1; off >>= 1)
            m = fmaxf(m, __shfl_xor(m, off));

        const float p = expf(s - m);
        ls[wv8][lane] = p;                    // own wave's row only
        __asm__ volatile("" ::: "memory");    // compiler barrier; DS in-order per wave

        // np.sum pairwise, n=64: 8 stride-8 serial chains + fixed combine
        float r0s = ls[wv8][0], r1s = ls[wv8][1], r2s = ls[wv8][2], r3s = ls[wv8][3];
        float r4s = ls[wv8][4], r5s = ls[wv8][5], r6s = ls[wv8][6], r7s = ls[wv8][7];
        #pragma unroll
        for (int i = 1; i < 8; ++i) {
            r0s += ls[wv8][8 * i + 0]; r1s += ls[wv8][8 * i + 1];
            r2s += ls[wv8][8 * i + 2]; r3s += ls[wv8][8 * i + 3];
            r4s += ls[wv8][8 * i + 4]; r5s += ls[wv8][8 * i + 5];
            r6s += ls[wv8][8 * i + 6]; r7s += ls[wv8][8 * i + 7];
        }
        const float S = ((r0s + r1s) + (r2s + r3s)) + ((r4s + r5s) + (r6s + r7s));

        const float score = p / S;            // IEEE f32 divide, matches np
        auxacc += score;

        // stable top-8: max with lowest-index tie-break (stable argsort)
        float cv = score;
        float myv = 0.f;
        int   myi = 0;
        #pragma unroll
        for (int i = 0; i < TOPK; ++i) {
            float v = cv;
            int idx = lane;
            #pragma unroll
            for (int off = 32; off >= 1; off >>= 1) {
                float v2 = __shfl_xor(v, off);
                int   i2 = __shfl_xor(idx, off);
                if (v2 > v || (v2 == v && i2 < idx)) { v = v2; idx = i2; }
            }
            if (lane == i)   { myv = v; myi = idx; }
            if (lane == idx) cv = -1.f;       // scores >= 0
        }

        // weight denom: np.sum n=8 -> serial ascending
        float S8 = 0.f;
        #pragma unroll
        for (int r = 0; r < TOPK; ++r) S8 += __shfl(myv, r);

        if (lane < TOPK) {
            const long o = gt * TOPK + lane;
            out[o]                     = (float)myi;   // expert_ids
            out[(long)NTOK * TOPK + o] = myv / S8;     // expert_weight
        }
    }

    atomicAdd(&wsum[(blk >> 6) * NEXP + lane], auxacc);

    // ---- last-block election computes the aux loss (saves a launch) ----
    __threadfence();
    __syncthreads();
    if (tid == 0) sdone = atomicAdd(done, 1);
    __syncthreads();
    if (sdone == gridDim.x - 1 && tid < 64) {
        float a = 0.f;
        #pragma unroll
        for (int b = 0; b < 4; ++b) {
            // atomic read-at-coherent-point (value unchanged: +0.0f)
            const float v = atomicAdd(&wsum[b * NEXP + tid], 0.f) * (1.0f / 4096.0f);
            a = fmaf(v, v, a);
        }
        #pragma unroll
        for (int off = 32; off >= 1; off >>= 1)
            a += __shfl_xor(a, off);
        if (tid == 0)
            out[2L * NTOK * TOPK] = a * 0.25f * (float)NEXP * 0.01f;
    }
}

__global__ void aux_finish(const float* __restrict__ wsum, float* __restrict__ out)
{
    const int lane = threadIdx.x;            // 64 threads (fallback path only)
    float a = 0.f;
    #pragma unroll
    for (int b = 0; b < 4; ++b) {
        const float v = wsum[b * NEXP + lane] * (1.0f / 4096.0f);
        a = fmaf(v, v, a);
    }
    #pragma unroll
    for (int off = 32; off >= 1; off >>= 1)
        a += __shfl_xor(a, off);
    if (lane == 0)
        out[2L * NTOK * TOPK] = a * 0.25f * (float)NEXP * 0.01f;
}

// ---------- fallback monolith (verified R10 kernel, used if ws too small) ----------
__global__ __launch_bounds__(1024, 1) void moe_gate_np(
    const float* __restrict__ h, const float* __restrict__ W,
    float* __restrict__ out, float* __restrict__ wsum)
{
#pragma clang fp contract(off)
    __shared__ float sA[BT * PADK];
    __shared__ float lg[BT][NEXP + 2];

    const int tid  = threadIdx.x;
    const int lane = tid & 63;
    const int wv   = tid >> 6;
    const int blk  = blockIdx.x;
    const long tok0 = (long)blk * BT;
    const float* hA = h + tok0 * DIM;

    const int e0 = __builtin_amdgcn_readfirstlane(wv) * EPW;
    const float* wb = W + (long)e0 * DIM;

    const int rs = tid >> 4;
    const int cs = (tid & 15) * 4;
    f4 pa = *(const f4*)(hA + (long)rs * DIM + cs);

    f2 a01[EPW], a23[EPW];
    #pragma unroll
    for (int j = 0; j < EPW; ++j) { a01[j] = (f2)(0.f); a23[j] = (f2)(0.f); }

    for (int kc = 0; kc < NCHUNK; ++kc) {
        __syncthreads();
        *(f4*)&sA[rs * PADK + cs] = pa;
        __syncthreads();
        if (kc + 1 < NCHUNK)
            pa = *(const f4*)(hA + (long)rs * DIM + (long)(kc + 1) * KC + cs);

        #pragma unroll
        for (int s = 0; s < 4; ++s) {
            const int kb = kc * KC + s * 16;
            f4 B[EPW][4];
            #pragma unroll
            for (int j = 0; j < EPW; ++j)
                #pragma unroll
                for (int q = 0; q < 4; ++q)
                    B[j][q] = *(const f4*)(wb + (long)j * DIM + kb + 4 * q);
            f4 af[4];
            const float* ab = &sA[lane * PADK + s * 16];
            #pragma unroll
            for (int v = 0; v < 4; ++v) af[v] = *(const f4*)(ab + 4 * v);
            f2 alo[4], ahi[4];
            #pragma unroll
            for (int v = 0; v < 4; ++v) {
                alo[v] = __builtin_shufflevector(af[v], af[v], 0, 1);
                ahi[v] = __builtin_shufflevector(af[v], af[v], 2, 3);
            }
            #pragma unroll
            for (int j = 0; j < EPW; ++j) {
                f2 blo[4], bhi[4];
                #pragma unroll
                for (int v = 0; v < 4; ++v) {
                    blo[v] = __builtin_shufflevector(B[j][v], B[j][v], 0, 1);
                    bhi[v] = __builtin_shufflevector(B[j][v], B[j][v], 2, 3);
                }
                f2 x;
                x = pk_add(pk_mul_sv(blo[3], alo[3]), a01[j]);
                x = pk_add(pk_mul_sv(blo[2], alo[2]), x);
                x = pk_add(pk_mul_sv(blo[1], alo[1]), x);
                a01[j] = pk_add(pk_mul_sv(blo[0], alo[0]), x);
                x = pk_add(pk_mul_sv(bhi[3], ahi[3]), a23[j]);
                x = pk_add(pk_mul_sv(bhi[2], ahi[2]), x);
                x = pk_add(pk_mul_sv(bhi[1], ahi[1]), x);
                a23[j] = pk_add(pk_mul_sv(bhi[0], ahi[0]), x);
            }
        }
    }

    #pragma unroll
    for (int j = 0; j < EPW; ++j) {
        f2 s2 = pk_add(a01[j], a23[j]);
        lg[lane][e0 + j] = s2.x + s2.y;
    }
    __syncthreads();

    float auxacc = 0.f;
    for (int tt = 0; tt < 4; ++tt) {
        const int t = wv * 4 + tt;
        const float s = lg[t][lane];
        float m = s;
        #pragma unroll
        for (int off = 32; off >= 1; off >>= 1)
            m = fmaxf(m, __shfl_xor(m, off));
        const float p = expf(s - m);
        lg[t][lane] = p;
        __asm__ volatile("" ::: "memory");
        float r0s = lg[t][0], r1s = lg[t][1], r2s = lg[t][2], r3s = lg[t][3];
        float r4s = lg[t][4], r5s = lg[t][5], r6s = lg[t][6], r7s = lg[t][7];
        #pragma unroll
        for (int i = 1; i < 8; ++i) {
            r0s += lg[t][8 * i + 0]; r1s += lg[t][8 * i + 1];
            r2s += lg[t][8 * i + 2]; r3s += lg[t][8 * i + 3];
            r4s += lg[t][8 * i + 4]; r5s += lg[t][8 * i + 5];
            r6s += lg[t][8 * i + 6]; r7s += lg[t][8 * i + 7];
        }
        const float S = ((r0s + r1s) + (r2s + r3s)) + ((r4s + r5s) + (r6s + r7s));
        const float score = p / S;
        auxacc += score;
        float cv = score;
        float myv = 0.f;
        int   myi = 0;
        #pragma unroll
        for (int i = 0; i < TOPK; ++i) {
            float v = cv;
            int idx = lane;
            #pragma unroll
            for (int off = 32; off >= 1; off >>= 1) {
                float v2 = __shfl_xor(v, off);
                int   i2 = __shfl_xor(idx, off);
                if (v2 > v || (v2 == v && i2 < idx)) { v = v2; idx = i2; }
            }
            if (lane == i)   { myv = v; myi = idx; }
            if (lane == idx) cv = -1.f;
        }
        float S8 = 0.f;
        #pragma unroll
        for (int r = 0; r < TOPK; ++r) S8 += __shfl(myv, r);
        if (lane < TOPK) {
            const long o = (tok0 + t) * TOPK + lane;
            out[o]                     = (float)myi;
            out[(long)NTOK * TOPK + o] = myv / S8;
        }
    }
    atomicAdd(&wsum[(blk >> 6) * NEXP + lane], auxacc);
}

extern "C" void kernel_launch(void* const* d_in, const int* in_sizes, int n_in,
                              void* d_out, int out_size, void* d_ws, size_t ws_size,
                              hipStream_t stream) {
    const float* h = (const float*)d_in[0];
    const float* W = (const float*)d_in[1];
    float* out  = (float*)d_out;
    float* wsum = (float*)d_ws;              // 256 f32 @ offset 0
    int*   done = (int*)((char*)d_ws + 1024);

    const size_t need = 4096 + (size_t)NTOK * NEXP * sizeof(float);

    hipMemsetAsync(d_ws, 0, 2048, stream);   // wsum + done counter
    if (ws_size >= need) {
        float* lgout = (float*)((char*)d_ws + 4096);   // 4 MB logits
        moe_gemm<<<NTILE * 4, 256, 0, stream>>>(h, W, lgout);
        softmax_topk_aux<<<NTOK / 64, 512, 0, stream>>>(lgout, out, wsum, done);
    } else {
        moe_gate_np<<<NTOK / BT, 1024, 0, stream>>>(h, W, out, wsum);
        aux_finish<<<1, 64, 0, stream>>>(wsum, out);
    }
}

// Round 17
// 143.184 us; speedup vs baseline: 2.3505x; 1.3518x over previous
//
#include <hip/hip_runtime.h>
#include <math.h>

#define NTOK 16384      // 4 * 4096 tokens
#define DIM 2048
#define NEXP 64
#define TOPK 8
#define BT 64           // tokens per block (lane = token)
#define KC 64           // four numpy 16-blocks per stage
#define NCHUNK (DIM / KC)   // 32
#define PADK 68         // LDS row stride floats
#define NBLK (NTOK / BT)    // 256 blocks, 1/CU, 16 waves/CU = 4/SIMD
#define EPW 4           // experts per wave (16 waves x 4 = 64)

typedef float f2 __attribute__((ext_vector_type(2)));
typedef float f4 __attribute__((ext_vector_type(4)));

// VOP3P packed f32: two independent IEEE f32 ops per instr, component-wise
// bit-identical to the scalar sequence. B comes in as an SGPR pair (src0).
__device__ __forceinline__ f2 pk_mul_sv(f2 bs, f2 av) {
    f2 d; asm("v_pk_mul_f32 %0, %1, %2" : "=v"(d) : "s"(bs), "v"(av)); return d;
}
__device__ __forceinline__ f2 pk_add(f2 a, f2 b) {
    f2 d; asm("v_pk_add_f32 %0, %1, %2" : "=v"(d) : "v"(a), "v"(b)); return d;
}

__global__ __launch_bounds__(1024, 1) void moe_gate_np(
    const float* __restrict__ h, const float* __restrict__ W,
    float* __restrict__ out, float* __restrict__ wsum)
{
#pragma clang fp contract(off)
    __shared__ float sA[2][BT * PADK];       // double-buffered h tile (34.8 KB)
    __shared__ float lg[BT][NEXP + 2];       // logits -> p values (16.9 KB)

    const int tid  = threadIdx.x;            // 0..1023
    const int lane = tid & 63;               // token within tile
    const int wv   = tid >> 6;               // 0..15: expert quartet
    const int blk  = blockIdx.x;
    const long tok0 = (long)blk * BT;
    const float* hA = h + tok0 * DIM;

    // wave-uniform expert base -> scalar (s_load) W accesses
    const int e0 = __builtin_amdgcn_readfirstlane(wv) * EPW;
    const float* wb = W + (long)e0 * DIM;

    // ---- A staging map: 1 f4 per thread per stage (64 rows x 64 cols) ----
    const int rs = tid >> 4;                 // 0..63
    const int cs = (tid & 15) * 4;           // 0..60

    // prologue: stage 0 -> buf0 (no barrier needed; loop-top barrier orders it),
    // then prefetch stage 1 into regs
    f4 pa = *(const f4*)(hA + (long)rs * DIM + cs);
    *(f4*)&sA[0][rs * PADK + cs] = pa;
    pa = *(const f4*)(hA + (long)rs * DIM + KC + cs);

    // accumulators: 4 experts x chain pairs (c0,c1) and (c2,c3)
    f2 a01[EPW], a23[EPW];
    #pragma unroll
    for (int j = 0; j < EPW; ++j) { a01[j] = (f2)(0.f); a23[j] = (f2)(0.f); }

    for (int kc = 0; kc < NCHUNK; ++kc) {
        __syncthreads();                     // single barrier per stage:
        const int cur = kc & 1;              // orders prev reads of buf[cur^1]
                                             // before this stage's writes
        if (kc + 1 < NCHUNK)                 // write next stage (regs -> LDS)
            *(f4*)&sA[cur ^ 1][rs * PADK + cs] = pa;
        if (kc + 2 < NCHUNK)                 // prefetch stage kc+2 (vmcnt-counted)
            pa = *(const f4*)(hA + (long)rs * DIM + (long)(kc + 2) * KC + cs);

        // 4 numpy 16-blocks per stage, strictly ascending k
        #pragma unroll
        for (int s = 0; s < 4; ++s) {
            const int kb = kc * KC + s * 16;

            // B batch: 4 experts x 4 f4, wave-uniform -> s_load (64 SGPR)
            f4 B[EPW][4];
            #pragma unroll
            for (int j = 0; j < EPW; ++j)
                #pragma unroll
                for (int q = 0; q < 4; ++q)
                    B[j][q] = *(const f4*)(wb + (long)j * DIM + kb + 4 * q);

            // A: this lane's token, 16 k-values (4 x ds_read_b128)
            f4 af[4];
            const float* ab = &sA[cur][lane * PADK + s * 16];
            #pragma unroll
            for (int v = 0; v < 4; ++v) af[v] = *(const f4*)(ab + 4 * v);

            f2 alo[4], ahi[4];               // .xy -> chains 0,1 ; .zw -> chains 2,3
            #pragma unroll
            for (int v = 0; v < 4; ++v) {
                alo[v] = __builtin_shufflevector(af[v], af[v], 0, 1);
                ahi[v] = __builtin_shufflevector(af[v], af[v], 2, 3);
            }

            #pragma unroll
            for (int j = 0; j < EPW; ++j) {
                f2 blo[4], bhi[4];           // uniform values -> SGPR pairs
                #pragma unroll
                for (int v = 0; v < 4; ++v) {
                    blo[v] = __builtin_shufflevector(B[j][v], B[j][v], 0, 1);
                    bhi[v] = __builtin_shufflevector(B[j][v], B[j][v], 2, 3);
                }
                f2 x;
                // chains 0,1: c = p0 + (p1 + (p2 + (p3 + c)))
                x = pk_add(pk_mul_sv(blo[3], alo[3]), a01[j]);
                x = pk_add(pk_mul_sv(blo[2], alo[2]), x);
                x = pk_add(pk_mul_sv(blo[1], alo[1]), x);
                a01[j] = pk_add(pk_mul_sv(blo[0], alo[0]), x);
                // chains 2,3
                x = pk_add(pk_mul_sv(bhi[3], ahi[3]), a23[j]);
                x = pk_add(pk_mul_sv(bhi[2], ahi[2]), x);
                x = pk_add(pk_mul_sv(bhi[1], ahi[1]), x);
                a23[j] = pk_add(pk_mul_sv(bhi[0], ahi[0]), x);
            }
        }
    }

    // horizontal combine: (c0+c2)+(c1+c3)  (npyv_sum_f32 SSE2 order)
    #pragma unroll
    for (int j = 0; j < EPW; ++j) {
        f2 s2 = pk_add(a01[j], a23[j]);       // (c0+c2, c1+c3)
        lg[lane][e0 + j] = s2.x + s2.y;
    }
    __syncthreads();

    // ---- per-token f32 softmax + stable top-8, numpy rounding orders ----
    float auxacc = 0.f;

    for (int tt = 0; tt < 4; ++tt) {
        const int t = wv * 4 + tt;            // 16 waves x 4 tokens
        const float s = lg[t][lane];          // lane = expert here

        float m = s;                          // max: exact, order-independent
        #pragma unroll
        for (int off = 32; off >= 1; off >>= 1)
            m = fmaxf(m, __shfl_xor(m, off));

        const float p = expf(s - m);
        lg[t][lane] = p;                      // own wave's rows only
        __asm__ volatile("" ::: "memory");    // compiler barrier; DS in-order per wave

        // np.sum pairwise, n=64: 8 stride-8 serial chains + fixed combine
        float r0s = lg[t][0], r1s = lg[t][1], r2s = lg[t][2], r3s = lg[t][3];
        float r4s = lg[t][4], r5s = lg[t][5], r6s = lg[t][6], r7s = lg[t][7];
        #pragma unroll
        for (int i = 1; i < 8; ++i) {
            r0s += lg[t][8 * i + 0]; r1s += lg[t][8 * i + 1];
            r2s += lg[t][8 * i + 2]; r3s += lg[t][8 * i + 3];
            r4s += lg[t][8 * i + 4]; r5s += lg[t][8 * i + 5];
            r6s += lg[t][8 * i + 6]; r7s += lg[t][8 * i + 7];
        }
        const float S = ((r0s + r1s) + (r2s + r3s)) + ((r4s + r5s) + (r6s + r7s));

        const float score = p / S;            // IEEE f32 divide, matches np
        auxacc += score;

        // stable top-8: max with lowest-index tie-break (stable argsort)
        float cv = score;
        float myv = 0.f;
        int   myi = 0;
        #pragma unroll
        for (int i = 0; i < TOPK; ++i) {
            float v = cv;
            int idx = lane;
            #pragma unroll
            for (int off = 32; off >= 1; off >>= 1) {
                float v2 = __shfl_xor(v, off);
                int   i2 = __shfl_xor(idx, off);
                if (v2 > v || (v2 == v && i2 < idx)) { v = v2; idx = i2; }
            }
            if (lane == i)   { myv = v; myi = idx; }
            if (lane == idx) cv = -1.f;       // scores >= 0
        }

        // weight denom: np.sum n=8 -> serial ascending
        float S8 = 0.f;
        #pragma unroll
        for (int r = 0; r < TOPK; ++r) S8 += __shfl(myv, r);

        if (lane < TOPK) {
            const long o = (tok0 + t) * TOPK + lane;
            out[o]                     = (float)myi;   // expert_ids
            out[(long)NTOK * TOPK + o] = myv / S8;     // expert_weight
        }
    }

    const int b = blk >> 6;                  // 64 blocks per batch row
    atomicAdd(&wsum[b * NEXP + lane], auxacc);
}

__global__ void aux_finish(const float* __restrict__ wsum, float* __restrict__ out)
{
    const int lane = threadIdx.x;            // 64 threads
    float a = 0.f;
    #pragma unroll
    for (int b = 0; b < 4; ++b) {
        const float v = wsum[b * NEXP + lane] * (1.0f / 4096.0f);
        a = fmaf(v, v, a);
    }
    #pragma unroll
    for (int off = 32; off >= 1; off >>= 1)
        a += __shfl_xor(a, off);
    if (lane == 0)
        out[2L * NTOK * TOPK] = a * 0.25f * (float)NEXP * 0.01f;
}

extern "C" void kernel_launch(void* const* d_in, const int* in_sizes, int n_in,
                              void* d_out, int out_size, void* d_ws, size_t ws_size,
                              hipStream_t stream) {
    const float* h = (const float*)d_in[0];
    const float* W = (const float*)d_in[1];
    float* out  = (float*)d_out;
    float* wsum = (float*)d_ws;              // 256 f32

    hipMemsetAsync(d_ws, 0, 1024, stream);
    moe_gate_np<<<NBLK, 1024, 0, stream>>>(h, W, out, wsum);
    aux_finish<<<1, 64, 0, stream>>>(wsum, out);
}